// Round 1
// baseline (184.471 us; speedup 1.0000x reference)
//
#include <hip/hip_runtime.h>

#define B 8
#define N 256
#define H 128
#define LAYERS 3
#define NF 6
#define EF 15
#define TD 4
#define FH 64

// ---------------------------------------------------------------------------
// deg[j] = sum_i (adj[j,i] > 0)
__global__ void k_deg(const int* __restrict__ adj, float* __restrict__ deg) {
    int j = blockIdx.x * blockDim.x + threadIdx.x;
    if (j < N) {
        float s = 0.f;
        for (int i = 0; i < N; ++i) s += (adj[j * N + i] > 0) ? 1.f : 0.f;
        deg[j] = s;
    }
}

// ---------------------------------------------------------------------------
// r_agg[b,j,c] = sum_i mask[j,i] * edge[b,i,j,12+c]
// block per (b,j); thread = i (256 threads)
__global__ void k_ragg(const int* __restrict__ adj, const float* __restrict__ edge,
                       float* __restrict__ ragg) {
    int bj = blockIdx.x;
    int b = bj / N, j = bj % N;
    int i = threadIdx.x;
    float v0 = 0.f, v1 = 0.f, v2 = 0.f;
    if (adj[j * N + i] > 0) {
        const float* e = edge + ((size_t)(b * N + i) * N + j) * EF + (EF - 3);
        v0 = e[0]; v1 = e[1]; v2 = e[2];
    }
    // wave (64-lane) reduction
    for (int o = 32; o > 0; o >>= 1) {
        v0 += __shfl_down(v0, o);
        v1 += __shfl_down(v1, o);
        v2 += __shfl_down(v2, o);
    }
    __shared__ float red[4][3];
    int lane = threadIdx.x & 63, wave = threadIdx.x >> 6;
    if (lane == 0) { red[wave][0] = v0; red[wave][1] = v1; red[wave][2] = v2; }
    __syncthreads();
    if (threadIdx.x == 0) {
        float s0 = 0.f, s1 = 0.f, s2 = 0.f;
        for (int w = 0; w < 4; ++w) { s0 += red[w][0]; s1 += red[w][1]; s2 += red[w][2]; }
        float* r = ragg + (size_t)bj * 3;
        r[0] = s0; r[1] = s1; r[2] = s2;
    }
}

// ---------------------------------------------------------------------------
// emb0[row,h] = relu(nf[row,:] @ W_emb[:,h] + b_emb[h]),  row in [0, B*N)
__global__ void k_emb0(const float* __restrict__ nf, const float* __restrict__ W,
                       const float* __restrict__ bias, float* __restrict__ emb) {
    int idx = blockIdx.x * 256 + threadIdx.x;   // B*N*H total threads
    int row = idx / H, h = idx % H;
    const float* x = nf + (size_t)row * NF;
    float acc = bias[h];
#pragma unroll
    for (int k = 0; k < NF; ++k) acc += x[k] * W[k * H + h];
    emb[idx] = fmaxf(acc, 0.f);
}

// ---------------------------------------------------------------------------
// tmp[row,h] = emb[row,:] @ We[:,h]   (We = msg_W[l][:H])
// block per row, 128 threads (h)
__global__ void k_we(const float* __restrict__ emb, const float* __restrict__ mwl,
                     float* __restrict__ tmp) {
    __shared__ float x[H];
    int row = blockIdx.x, h = threadIdx.x;
    x[h] = emb[(size_t)row * H + h];
    __syncthreads();
    float acc = 0.f;
    for (int k = 0; k < H; ++k) acc += x[k] * mwl[k * H + h];
    tmp[(size_t)row * H + h] = acc;
}

// ---------------------------------------------------------------------------
// msg[b,j,h] = sum_i mask[j,i]*tmp[b,i,h] + ragg[b,j,:]@Wr[:,h] + deg[j]*msg_b[l,h]
// block per (b,j), 128 threads (h)
__global__ void k_msg(const int* __restrict__ adj, const float* __restrict__ tmp,
                      const float* __restrict__ ragg, const float* __restrict__ deg,
                      const float* __restrict__ mwl, const float* __restrict__ mbl,
                      float* __restrict__ msgout) {
    __shared__ float m[N];
    int bj = blockIdx.x;
    int b = bj / N, j = bj % N;
    int h = threadIdx.x;
    m[h]       = (adj[j * N + h] > 0) ? 1.f : 0.f;
    m[h + 128] = (adj[j * N + h + 128] > 0) ? 1.f : 0.f;
    __syncthreads();
    const float* ra = ragg + (size_t)bj * 3;
    float acc = deg[j] * mbl[h];
    acc += ra[0] * mwl[(H + 0) * H + h];
    acc += ra[1] * mwl[(H + 1) * H + h];
    acc += ra[2] * mwl[(H + 2) * H + h];
    const float* tb = tmp + (size_t)b * N * H + h;
    for (int i = 0; i < N; ++i) {
        if (m[i] != 0.f) acc += tb[(size_t)i * H];   // block-uniform branch
    }
    msgout[(size_t)bj * H + h] = acc;
}

// ---------------------------------------------------------------------------
// emb_new[row,h] = relu(emb[row,:]@updW[:H,h] + msg[row,:]@updW[H:,h] + upd_b[h])
// block per row, 128 threads (h)
__global__ void k_upd(const float* __restrict__ emb, const float* __restrict__ msg,
                      const float* __restrict__ uwl, const float* __restrict__ ubl,
                      float* __restrict__ out) {
    __shared__ float e[H], mm[H];
    int row = blockIdx.x, h = threadIdx.x;
    e[h]  = emb[(size_t)row * H + h];
    mm[h] = msg[(size_t)row * H + h];
    __syncthreads();
    float acc = ubl[h];
    for (int k = 0; k < H; ++k) acc += e[k] * uwl[k * H + h];
    for (int k = 0; k < H; ++k) acc += mm[k] * uwl[(H + k) * H + h];
    out[(size_t)row * H + h] = fmaxf(acc, 0.f);
}

// ---------------------------------------------------------------------------
// hi[row,f] = emb[row,:] @ W1[:H, f] ; hj[row,f] = emb[row,:] @ W1[H:2H, f]
// block per row, 128 threads: tid<64 -> hi, tid>=64 -> hj
__global__ void k_hij(const float* __restrict__ emb, const float* __restrict__ W1,
                      float* __restrict__ hi, float* __restrict__ hj) {
    __shared__ float e[H];
    int row = blockIdx.x, t = threadIdx.x;
    e[t] = emb[(size_t)row * H + t];
    __syncthreads();
    int f = t & 63;
    const float* W = W1 + (t < 64 ? 0 : H * FH);
    float acc = 0.f;
    for (int k = 0; k < H; ++k) acc += e[k] * W[k * FH + f];
    float* dst = (t < 64) ? hi : hj;
    dst[(size_t)row * FH + f] = acc;
}

// ---------------------------------------------------------------------------
// flows[b,i,j] = relu( relu(hi[b,i,:] + hj[b,j,:] + er@Wr1 + tf@Wt + b1) @ W2 + b2 )
// block = 16x16 (i,j) tile of one batch; 256 threads
__global__ void k_final(const float* __restrict__ hi, const float* __restrict__ hj,
                        const float* __restrict__ edge, const float* __restrict__ temporal,
                        const float* __restrict__ W1, const float* __restrict__ b1,
                        const float* __restrict__ W2, const float* __restrict__ b2,
                        float* __restrict__ flows) {
    __shared__ float hisz[16][65], hjsz[16][65];
    __shared__ float wr[3][FH], wt[4][FH], bb[FH], w2[FH];
    int blk = blockIdx.x;
    int jt = blk % (N / 16); blk /= (N / 16);
    int it = blk % (N / 16);
    int b  = blk / (N / 16);
    int tid = threadIdx.x;
#pragma unroll
    for (int r = 0; r < 4; ++r) {
        int idx = r * 256 + tid;
        int rr = idx >> 6, f = idx & 63;
        hisz[rr][f] = hi[((size_t)b * N + it * 16 + rr) * FH + f];
        hjsz[rr][f] = hj[((size_t)b * N + jt * 16 + rr) * FH + f];
    }
    if (tid < 3 * FH) wr[tid >> 6][tid & 63] = W1[(2 * H) * FH + tid];
    wt[tid >> 6][tid & 63] = W1[(2 * H + 3) * FH + tid];   // 256 = 4*FH threads
    if (tid < FH) { bb[tid] = b1[tid]; w2[tid] = W2[tid]; }
    __syncthreads();
    int tj = tid & 15, ti = tid >> 4;
    int i = it * 16 + ti, j = jt * 16 + tj;
    size_t pij = (size_t)(b * N + i) * N + j;
    const float* e = edge + pij * EF + (EF - 3);
    float er0 = e[0], er1 = e[1], er2 = e[2];
    float4 tf = *(const float4*)(temporal + pij * TD);
    float acc = 0.f;
#pragma unroll
    for (int f = 0; f < FH; ++f) {
        float v = hisz[ti][f] + hjsz[tj][f] + bb[f]
                + er0 * wr[0][f] + er1 * wr[1][f] + er2 * wr[2][f]
                + tf.x * wt[0][f] + tf.y * wt[1][f] + tf.z * wt[2][f] + tf.w * wt[3][f];
        acc += fmaxf(v, 0.f) * w2[f];
    }
    flows[pij] = fmaxf(acc + b2[0], 0.f);
}

// ---------------------------------------------------------------------------
extern "C" void kernel_launch(void* const* d_in, const int* in_sizes, int n_in,
                              void* d_out, int out_size, void* d_ws, size_t ws_size,
                              hipStream_t stream) {
    const float* nf       = (const float*)d_in[0];
    const float* edge     = (const float*)d_in[1];
    const float* temporal = (const float*)d_in[2];
    const int*   adj      = (const int*)d_in[3];
    const float* W_emb    = (const float*)d_in[4];
    const float* b_emb    = (const float*)d_in[5];
    const float* msg_W    = (const float*)d_in[6];
    const float* msg_b    = (const float*)d_in[7];
    const float* upd_W    = (const float*)d_in[8];
    const float* upd_b    = (const float*)d_in[9];
    const float* W1       = (const float*)d_in[10];
    const float* b1       = (const float*)d_in[11];
    const float* W2       = (const float*)d_in[12];
    const float* b2       = (const float*)d_in[13];
    float* out = (float*)d_out;

    float* ws = (float*)d_ws;
    float* deg  = ws; ws += 256;
    float* ragg = ws; ws += B * N * 3;
    float* embA = ws; ws += B * N * H;
    float* embB = ws; ws += B * N * H;
    float* tmp  = ws; ws += B * N * H;
    float* msg  = ws; ws += B * N * H;
    float* hi   = ws; ws += B * N * FH;
    float* hj   = ws; ws += B * N * FH;

    k_deg<<<1, 256, 0, stream>>>(adj, deg);
    k_ragg<<<B * N, 256, 0, stream>>>(adj, edge, ragg);
    k_emb0<<<(B * N * H) / 256, 256, 0, stream>>>(nf, W_emb, b_emb, embA);

    float* cur = embA;
    float* nxt = embB;
    for (int l = 0; l < LAYERS; ++l) {
        const float* mwl = msg_W + (size_t)l * (H + 3) * H;
        const float* mbl = msg_b + (size_t)l * H;
        const float* uwl = upd_W + (size_t)l * 2 * H * H;
        const float* ubl = upd_b + (size_t)l * H;
        k_we<<<B * N, H, 0, stream>>>(cur, mwl, tmp);
        k_msg<<<B * N, H, 0, stream>>>(adj, tmp, ragg, deg, mwl, mbl, msg);
        k_upd<<<B * N, H, 0, stream>>>(cur, msg, uwl, ubl, nxt);
        float* t = cur; cur = nxt; nxt = t;
    }

    k_hij<<<B * N, H, 0, stream>>>(cur, W1, hi, hj);
    k_final<<<B * (N / 16) * (N / 16), 256, 0, stream>>>(hi, hj, edge, temporal,
                                                         W1, b1, W2, b2, out);
}

// Round 2
// 149.338 us; speedup vs baseline: 1.2353x; 1.2353x over previous
//
#include <hip/hip_runtime.h>

#define B 8
#define N 256
#define H 128
#define LAYERS 3
#define NF 6
#define EF 15
#define TD 4
#define FH 64
#define M (B*N)        // 2048 rows

// ---------------------------------------------------------------------------
// k_pre: block b (256 blocks, 256 thr):
//   deg[b] = sum_j adj[b*N+j]>0            (coalesced row read + reduce)
//   maskT[b*N + j] = adj[j*N + b] > 0      (transpose; write coalesced)
//   zero ragg slice
__global__ void k_pre(const int* __restrict__ adj, float* __restrict__ deg,
                      float* __restrict__ maskT, float* __restrict__ ragg) {
    int b = blockIdx.x, t = threadIdx.x;
    // deg
    float v = (adj[b * N + t] > 0) ? 1.f : 0.f;
    for (int o = 32; o > 0; o >>= 1) v += __shfl_down(v, o);
    __shared__ float red[4];
    if ((t & 63) == 0) red[t >> 6] = v;
    __syncthreads();
    if (t == 0) deg[b] = red[0] + red[1] + red[2] + red[3];
    // maskT row b: maskT[b][j] = adj[j][b]
    maskT[b * N + t] = (adj[t * N + b] > 0) ? 1.f : 0.f;
    // zero ragg (B*N*3 = 6144 floats; 24 per block)
    if (t < 24) ragg[b * 24 + t] = 0.f;
}

// ---------------------------------------------------------------------------
// k_erel_ragg: block = (b, ichunk of 8 i's). thread j = tid.
// Streams edge records once: writes compact erel[(b,i,j),3] and accumulates
// register partials of r_agg[b,j,c] = sum_i mask[j,i]*erel, atomicAdd at end.
__global__ void k_erel_ragg(const float* __restrict__ edge, const float* __restrict__ maskT,
                            float* __restrict__ erel, float* __restrict__ ragg) {
    int blk = blockIdx.x;
    int b = blk >> 5, ic = blk & 31;
    int j = threadIdx.x;
    float r0 = 0.f, r1 = 0.f, r2 = 0.f;
#pragma unroll
    for (int ii = 0; ii < 8; ++ii) {
        int i = ic * 8 + ii;
        size_t base = ((size_t)(b * N + i) * N + j);
        const float* e = edge + base * EF + (EF - 3);
        float e0 = e[0], e1 = e[1], e2 = e[2];
        float* d = erel + base * 3;
        d[0] = e0; d[1] = e1; d[2] = e2;
        float m = maskT[i * N + j];
        r0 += m * e0; r1 += m * e1; r2 += m * e2;
    }
    float* r = ragg + (size_t)(b * N + j) * 3;
    atomicAdd(r + 0, r0);
    atomicAdd(r + 1, r1);
    atomicAdd(r + 2, r2);
}

// ---------------------------------------------------------------------------
// emb0[row,h] = relu(nf[row,:] @ W_emb[:,h] + b_emb[h])
__global__ void k_emb0(const float* __restrict__ nf, const float* __restrict__ W,
                       const float* __restrict__ bias, float* __restrict__ emb) {
    int idx = blockIdx.x * 256 + threadIdx.x;
    int row = idx / H, h = idx % H;
    const float* x = nf + (size_t)row * NF;
    float acc = bias[h];
#pragma unroll
    for (int k = 0; k < NF; ++k) acc += x[k] * W[k * H + h];
    emb[idx] = fmaxf(acc, 0.f);
}

// ---------------------------------------------------------------------------
// tmp = emb @ We  (M=2048, K=128, N=128). 256 blocks x 8 rows.
// thread: cg=tid&31 -> cols cg*4..+3 ; rg=tid>>5 -> row r0+rg.
__global__ void k_we(const float* __restrict__ emb, const float* __restrict__ We,
                     float* __restrict__ tmp) {
    int cg = threadIdx.x & 31, rg = threadIdx.x >> 5;
    int row = blockIdx.x * 8 + rg;
    int c0 = cg * 4;
    const float* a = emb + (size_t)row * H;
    float4 acc = {0.f, 0.f, 0.f, 0.f};
#pragma unroll 4
    for (int k = 0; k < H; k += 4) {
        float4 av = *(const float4*)(a + k);
        float4 w0 = *(const float4*)(We + (size_t)(k + 0) * H + c0);
        float4 w1 = *(const float4*)(We + (size_t)(k + 1) * H + c0);
        float4 w2 = *(const float4*)(We + (size_t)(k + 2) * H + c0);
        float4 w3 = *(const float4*)(We + (size_t)(k + 3) * H + c0);
        acc.x += av.x * w0.x + av.y * w1.x + av.z * w2.x + av.w * w3.x;
        acc.y += av.x * w0.y + av.y * w1.y + av.z * w2.y + av.w * w3.y;
        acc.z += av.x * w0.z + av.y * w1.z + av.z * w2.z + av.w * w3.z;
        acc.w += av.x * w0.w + av.y * w1.w + av.z * w2.w + av.w * w3.w;
    }
    *(float4*)(tmp + (size_t)row * H + c0) = acc;
}

// ---------------------------------------------------------------------------
// Fused: msg[b,j,:] = mask[j,:] @ tmp[b] + ragg[b,j,:]@Wr + deg[j]*msg_b
//        emb_new[b,j,:] = relu(concat(emb[b,j,:], msg[b,j,:]) @ updW + upd_b)
// block = (b, jtile of 8). 256 thr: cg=tid&31 (4 cols), rg=tid>>5 (j-local).
__global__ void k_msgupd(const int* __restrict__ adj, const float* __restrict__ tmp,
                         const float* __restrict__ ragg, const float* __restrict__ deg,
                         const float* __restrict__ mwl, const float* __restrict__ mbl,
                         const float* __restrict__ emb, const float* __restrict__ uwl,
                         const float* __restrict__ ubl, float* __restrict__ out) {
    __shared__ float smsg[8][H];
    int blk = blockIdx.x;
    int b = blk >> 5, jt = blk & 31;
    int cg = threadIdx.x & 31, rg = threadIdx.x >> 5;
    int j = jt * 8 + rg;
    int c0 = cg * 4;
    size_t rowj = (size_t)(b * N + j);

    // bias terms: deg[j]*msg_b[c] + ragg[b,j,:] @ Wr[:,c]
    const float* ra = ragg + rowj * 3;
    float ra0 = ra[0], ra1 = ra[1], ra2 = ra[2], dg = deg[j];
    float4 mb4 = *(const float4*)(mbl + c0);
    float4 wr0 = *(const float4*)(mwl + (size_t)(H + 0) * H + c0);
    float4 wr1 = *(const float4*)(mwl + (size_t)(H + 1) * H + c0);
    float4 wr2 = *(const float4*)(mwl + (size_t)(H + 2) * H + c0);
    float4 acc;
    acc.x = dg * mb4.x + ra0 * wr0.x + ra1 * wr1.x + ra2 * wr2.x;
    acc.y = dg * mb4.y + ra0 * wr0.y + ra1 * wr1.y + ra2 * wr2.y;
    acc.z = dg * mb4.z + ra0 * wr0.z + ra1 * wr1.z + ra2 * wr2.z;
    acc.w = dg * mb4.w + ra0 * wr0.w + ra1 * wr1.w + ra2 * wr2.w;

    // masked aggregation over i
    const int* arow = adj + (size_t)j * N;
    const float* tb = tmp + (size_t)b * N * H + c0;
#pragma unroll 2
    for (int i = 0; i < N; i += 4) {
        int4 mv = *(const int4*)(arow + i);
        float m0 = (mv.x > 0) ? 1.f : 0.f;
        float m1 = (mv.y > 0) ? 1.f : 0.f;
        float m2 = (mv.z > 0) ? 1.f : 0.f;
        float m3 = (mv.w > 0) ? 1.f : 0.f;
        float4 t0 = *(const float4*)(tb + (size_t)(i + 0) * H);
        float4 t1 = *(const float4*)(tb + (size_t)(i + 1) * H);
        float4 t2 = *(const float4*)(tb + (size_t)(i + 2) * H);
        float4 t3 = *(const float4*)(tb + (size_t)(i + 3) * H);
        acc.x += m0 * t0.x + m1 * t1.x + m2 * t2.x + m3 * t3.x;
        acc.y += m0 * t0.y + m1 * t1.y + m2 * t2.y + m3 * t3.y;
        acc.z += m0 * t0.z + m1 * t1.z + m2 * t2.z + m3 * t3.z;
        acc.w += m0 * t0.w + m1 * t1.w + m2 * t2.w + m3 * t3.w;
    }
    *(float4*)(&smsg[rg][c0]) = acc;
    __syncthreads();

    // update GEMM: K=256 (emb row || msg row)
    float4 o4 = *(const float4*)(ubl + c0);
    const float* arow2 = emb + rowj * H;
#pragma unroll 4
    for (int k = 0; k < H; k += 4) {
        float4 av = *(const float4*)(arow2 + k);
        float4 w0 = *(const float4*)(uwl + (size_t)(k + 0) * H + c0);
        float4 w1 = *(const float4*)(uwl + (size_t)(k + 1) * H + c0);
        float4 w2 = *(const float4*)(uwl + (size_t)(k + 2) * H + c0);
        float4 w3 = *(const float4*)(uwl + (size_t)(k + 3) * H + c0);
        o4.x += av.x * w0.x + av.y * w1.x + av.z * w2.x + av.w * w3.x;
        o4.y += av.x * w0.y + av.y * w1.y + av.z * w2.y + av.w * w3.y;
        o4.z += av.x * w0.z + av.y * w1.z + av.z * w2.z + av.w * w3.z;
        o4.w += av.x * w0.w + av.y * w1.w + av.z * w2.w + av.w * w3.w;
    }
#pragma unroll 4
    for (int k = 0; k < H; k += 4) {
        float4 av = *(const float4*)(&smsg[rg][k]);
        float4 w0 = *(const float4*)(uwl + (size_t)(H + k + 0) * H + c0);
        float4 w1 = *(const float4*)(uwl + (size_t)(H + k + 1) * H + c0);
        float4 w2 = *(const float4*)(uwl + (size_t)(H + k + 2) * H + c0);
        float4 w3 = *(const float4*)(uwl + (size_t)(H + k + 3) * H + c0);
        o4.x += av.x * w0.x + av.y * w1.x + av.z * w2.x + av.w * w3.x;
        o4.y += av.x * w0.y + av.y * w1.y + av.z * w2.y + av.w * w3.y;
        o4.z += av.x * w0.z + av.y * w1.z + av.z * w2.z + av.w * w3.z;
        o4.w += av.x * w0.w + av.y * w1.w + av.z * w2.w + av.w * w3.w;
    }
    o4.x = fmaxf(o4.x, 0.f); o4.y = fmaxf(o4.y, 0.f);
    o4.z = fmaxf(o4.z, 0.f); o4.w = fmaxf(o4.w, 0.f);
    *(float4*)(out + rowj * H + c0) = o4;
}

// ---------------------------------------------------------------------------
// hi = emb @ W1[:H], hj = emb @ W1[H:2H]. 256 blocks x 8 rows.
// cg<16 -> hi cols, cg>=16 -> hj cols.
__global__ void k_hij(const float* __restrict__ emb, const float* __restrict__ W1,
                      float* __restrict__ hi, float* __restrict__ hj) {
    int cg = threadIdx.x & 31, rg = threadIdx.x >> 5;
    int row = blockIdx.x * 8 + rg;
    int c0 = cg * 4;
    int kbase = (c0 < FH) ? 0 : H;
    int cc = c0 & (FH - 1);
    const float* a = emb + (size_t)row * H;
    float4 acc = {0.f, 0.f, 0.f, 0.f};
#pragma unroll 4
    for (int k = 0; k < H; k += 4) {
        float4 av = *(const float4*)(a + k);
        float4 w0 = *(const float4*)(W1 + (size_t)(kbase + k + 0) * FH + cc);
        float4 w1 = *(const float4*)(W1 + (size_t)(kbase + k + 1) * FH + cc);
        float4 w2 = *(const float4*)(W1 + (size_t)(kbase + k + 2) * FH + cc);
        float4 w3 = *(const float4*)(W1 + (size_t)(kbase + k + 3) * FH + cc);
        acc.x += av.x * w0.x + av.y * w1.x + av.z * w2.x + av.w * w3.x;
        acc.y += av.x * w0.y + av.y * w1.y + av.z * w2.y + av.w * w3.y;
        acc.z += av.x * w0.z + av.y * w1.z + av.z * w2.z + av.w * w3.z;
        acc.w += av.x * w0.w + av.y * w1.w + av.z * w2.w + av.w * w3.w;
    }
    float* dst = (c0 < FH) ? hi : hj;
    *(float4*)(dst + (size_t)row * FH + cc) = acc;
}

// ---------------------------------------------------------------------------
// flows[b,i,j] = relu(relu(hi[b,i]+hj[b,j]+erel@Wr1+tf@Wt+b1)@W2+b2)
__global__ void k_final(const float* __restrict__ hi, const float* __restrict__ hj,
                        const float* __restrict__ erel, const float* __restrict__ temporal,
                        const float* __restrict__ W1, const float* __restrict__ b1,
                        const float* __restrict__ W2, const float* __restrict__ b2,
                        float* __restrict__ flows) {
    __shared__ float hisz[16][FH + 1], hjsz[16][FH + 1];
    __shared__ float wr[3][FH], wt[4][FH], bb[FH], w2[FH];
    int blk = blockIdx.x;
    int jt = blk % (N / 16); blk /= (N / 16);
    int it = blk % (N / 16);
    int b  = blk / (N / 16);
    int tid = threadIdx.x;
#pragma unroll
    for (int r = 0; r < 4; ++r) {
        int idx = r * 256 + tid;
        int rr = idx >> 6, f = idx & 63;
        hisz[rr][f] = hi[((size_t)(b * N) + it * 16 + rr) * FH + f];
        hjsz[rr][f] = hj[((size_t)(b * N) + jt * 16 + rr) * FH + f];
    }
    if (tid < 3 * FH) wr[tid >> 6][tid & 63] = W1[(2 * H) * FH + tid];
    wt[tid >> 6][tid & 63] = W1[(2 * H + 3) * FH + tid];
    if (tid < FH) { bb[tid] = b1[tid]; w2[tid] = W2[tid]; }
    __syncthreads();
    int tj = tid & 15, ti = tid >> 4;
    int i = it * 16 + ti, j = jt * 16 + tj;
    size_t pij = (size_t)(b * N + i) * N + j;
    const float* e = erel + pij * 3;
    float er0 = e[0], er1 = e[1], er2 = e[2];
    float4 tf = *(const float4*)(temporal + pij * TD);
    float acc = 0.f;
#pragma unroll
    for (int f = 0; f < FH; ++f) {
        float v = hisz[ti][f] + hjsz[tj][f] + bb[f]
                + er0 * wr[0][f] + er1 * wr[1][f] + er2 * wr[2][f]
                + tf.x * wt[0][f] + tf.y * wt[1][f] + tf.z * wt[2][f] + tf.w * wt[3][f];
        acc += fmaxf(v, 0.f) * w2[f];
    }
    flows[pij] = fmaxf(acc + b2[0], 0.f);
}

// ---------------------------------------------------------------------------
extern "C" void kernel_launch(void* const* d_in, const int* in_sizes, int n_in,
                              void* d_out, int out_size, void* d_ws, size_t ws_size,
                              hipStream_t stream) {
    const float* nf       = (const float*)d_in[0];
    const float* edge     = (const float*)d_in[1];
    const float* temporal = (const float*)d_in[2];
    const int*   adj      = (const int*)d_in[3];
    const float* W_emb    = (const float*)d_in[4];
    const float* b_emb    = (const float*)d_in[5];
    const float* msg_W    = (const float*)d_in[6];
    const float* msg_b    = (const float*)d_in[7];
    const float* upd_W    = (const float*)d_in[8];
    const float* upd_b    = (const float*)d_in[9];
    const float* W1       = (const float*)d_in[10];
    const float* b1       = (const float*)d_in[11];
    const float* W2       = (const float*)d_in[12];
    const float* b2       = (const float*)d_in[13];
    float* out = (float*)d_out;

    float* ws = (float*)d_ws;
    float* deg   = ws; ws += 256;
    float* ragg  = ws; ws += B * N * 3;
    float* maskT = ws; ws += N * N;
    float* embA  = ws; ws += M * H;
    float* embB  = ws; ws += M * H;
    float* tmp   = ws; ws += M * H;
    float* hi    = ws; ws += M * FH;
    float* hj    = ws; ws += M * FH;
    float* erel  = ws; ws += B * N * N * 3;

    k_pre<<<N, 256, 0, stream>>>(adj, deg, maskT, ragg);
    k_erel_ragg<<<256, 256, 0, stream>>>(edge, maskT, erel, ragg);
    k_emb0<<<(M * H) / 256, 256, 0, stream>>>(nf, W_emb, b_emb, embA);

    float* cur = embA;
    float* nxt = embB;
    for (int l = 0; l < LAYERS; ++l) {
        const float* mwl = msg_W + (size_t)l * (H + 3) * H;
        const float* mbl = msg_b + (size_t)l * H;
        const float* uwl = upd_W + (size_t)l * 2 * H * H;
        const float* ubl = upd_b + (size_t)l * H;
        k_we<<<M / 8, 256, 0, stream>>>(cur, mwl, tmp);
        k_msgupd<<<M / 8, 256, 0, stream>>>(adj, tmp, ragg, deg, mwl, mbl,
                                            cur, uwl, ubl, nxt);
        float* t = cur; cur = nxt; nxt = t;
    }

    k_hij<<<M / 8, 256, 0, stream>>>(cur, W1, hi, hj);
    k_final<<<B * (N / 16) * (N / 16), 256, 0, stream>>>(hi, hj, erel, temporal,
                                                         W1, b1, W2, b2, out);
}